// Round 17
// baseline (271.078 us; speedup 1.0000x reference)
//
#include <hip/hip_runtime.h>
#include <hip/hip_bf16.h>

// CLIP loss: B=8192, D=1024, temp=0.5.
// loss = mean_i [ 0.5*(log sum_j exp(s_ij) + log sum_j exp(s_ji)) - s_ii ],
// s = (zi_n @ zj_n^T) * 2.  |s| <= 2 -> exp safe, no max trick.
//
// R17: ZERO-LDS, ZERO-BARRIER GEMM. All schedule variants with barriers
// (R1-R15) pin at ~75% stall; R16 proved direct-global MFMA operands are
// correct (absmax 0.0) but kept the drain-barrier. Here: every wave loads
// af/bfr straight from L2 (supertile-hot), full K unroll (8 tiles), no
// inter-wave sync until the tiny epilogue reduce. Compiler pipelines loads
// across the whole stream with counted vmcnts; 4 independent waves/block.
// L2-traffic floor: 16384 waves x 8 x 16KB = 2.15GB @ 34.5TB/s = 62us.
// Operand shapes = the allocator-proven set (af[4],bfr[4],acc[4][4],
// 256thr,(256,2)): only af's source changes (global, mirroring R16's bfr).
//
// ws: [0,8M) zi8 (x2 temp folded), [8M,16M) zj8, [16M,18M) rp[64][8192],
//     [18M,20M) cp[64][8192], [20M,+32K) dg[8192], then part[32].

using f32x4 = __attribute__((ext_vector_type(4))) float;
using i32x8 = __attribute__((ext_vector_type(8))) int;
using i32x4 = __attribute__((ext_vector_type(4))) int;

#define USCL 0x7F7F7F7Fu   // E8M0 = 127 -> scale 1.0 in every byte

// ---- kernel 1: row-normalize fp32 -> fp8 e4m3, extra scale folded ----
__global__ __launch_bounds__(256) void clip_norm_k(const float* __restrict__ in,
                                                   unsigned int* __restrict__ out,
                                                   float extra) {
    int row = blockIdx.x;
    const float4* ip = reinterpret_cast<const float4*>(in + (size_t)row * 1024);
    float4 v = ip[threadIdx.x];
    float ss = v.x * v.x + v.y * v.y + v.z * v.z + v.w * v.w;
    #pragma unroll
    for (int o = 1; o < 64; o <<= 1) ss += __shfl_xor(ss, o);
    __shared__ float sb[4];
    if ((threadIdx.x & 63) == 0) sb[threadIdx.x >> 6] = ss;
    __syncthreads();
    float tot = sb[0] + sb[1] + sb[2] + sb[3];
    float scl = extra / fmaxf(sqrtf(tot), 1e-12f);
    int p = __builtin_amdgcn_cvt_pk_fp8_f32(v.x * scl, v.y * scl, 0, false);
    p = __builtin_amdgcn_cvt_pk_fp8_f32(v.z * scl, v.w * scl, p, true);
    out[(size_t)row * 256 + threadIdx.x] = (unsigned int)p;
}

// Fragment direct from global (R16-verified): 32B contiguous per lane.
// row relative to panel base; khi = l>>4 selects the 32B k-chunk.
__device__ __forceinline__ i32x8 ldG(const unsigned char* G, int row, int khi,
                                     int ktB) {
    const unsigned char* p = G + (size_t)row * 1024 + ktB + khi * 32;
    i32x4 lo = *reinterpret_cast<const i32x4*>(p);
    i32x4 hi = *reinterpret_cast<const i32x4*>(p + 16);
    i32x8 r;
    r[0] = lo[0]; r[1] = lo[1]; r[2] = lo[2]; r[3] = lo[3];
    r[4] = hi[0]; r[5] = hi[1]; r[6] = hi[2]; r[7] = hi[3];
    return r;
}

__global__ __launch_bounds__(256, 2) void clip_gemm_k(
    const unsigned char* __restrict__ A,   // zi8 [8192][1024]
    const unsigned char* __restrict__ Bm,  // zj8 [8192][1024]
    float* __restrict__ rp, float* __restrict__ cp, float* __restrict__ dg) {
    __shared__ float rbuf[2][128];
    __shared__ float cbuf[2][128];

    // L2-supertile swizzle (R10-verified: FETCH 266->37 MB).
    const int c_x = blockIdx.x & 7;
    const int q = blockIdx.x >> 3;           // 0..511
    const int s = q >> 6;                    // supertile 0..7 (temporal)
    const int p = q & 63;                    // position in 8x8 supertile
    const int bi = c_x * 8 + (p >> 3);       // 0..63
    const int bj = s * 8 + (p & 7);          // 0..63
    const int tid = threadIdx.x;
    const int l = tid & 63, w = tid >> 6;
    const int wm = w >> 1, wn = w & 1;       // 2x2 wave grid, per-wave 64x64
    const int llo = l & 15, khi = l >> 4;

    f32x4 acc[4][4] = {};

    const unsigned char* Ag = A + (size_t)(bi * 128) * 1024;
    const unsigned char* Bg = Bm + (size_t)(bj * 128) * 1024;

    // barrier-free K stream: 8 tiles fully unrolled; compiler hoists loads
    // with counted vmcnts; waves never synchronize.
    #pragma unroll
    for (int t = 0; t < 8; ++t) {
        i32x8 af[4], bfr[4];
        #pragma unroll
        for (int m = 0; m < 4; ++m)
            af[m] = ldG(Ag, wm * 64 + m * 16 + llo, khi, t * 128);
        #pragma unroll
        for (int n = 0; n < 4; ++n)
            bfr[n] = ldG(Bg, wn * 64 + n * 16 + llo, khi, t * 128);
        #pragma unroll
        for (int m = 0; m < 4; ++m)
            #pragma unroll
            for (int n = 0; n < 4; ++n)
                acc[m][n] = __builtin_amdgcn_mfma_scale_f32_16x16x128_f8f6f4(
                    af[m], bfr[n], acc[m][n], 0, 0, 0, USCL, 0, USCL);
    }

    // ---- epilogue (R9/R10-verified 16x16 C/D mapping: col=llo, row=khi*4+reg) ----
    if (bi == bj && wm == wn) {
        #pragma unroll
        for (int m = 0; m < 4; ++m)
            #pragma unroll
            for (int r = 0; r < 4; ++r)
                if (khi * 4 + r == llo)
                    dg[bi * 128 + wm * 64 + m * 16 + llo] = acc[m][m][r];
    }

    #pragma unroll
    for (int m = 0; m < 4; ++m)
        #pragma unroll
        for (int n = 0; n < 4; ++n)
            #pragma unroll
            for (int r = 0; r < 4; ++r)
                acc[m][n][r] = exp2f(acc[m][n][r] * 1.44269504f);

    // row sums over this wave's 64 cols
    #pragma unroll
    for (int m = 0; m < 4; ++m) {
        #pragma unroll
        for (int r = 0; r < 4; ++r) {
            float v = acc[m][0][r] + acc[m][1][r] + acc[m][2][r] + acc[m][3][r];
            v += __shfl_xor(v, 1);
            v += __shfl_xor(v, 2);
            v += __shfl_xor(v, 4);
            v += __shfl_xor(v, 8);
            if (llo == 0) rbuf[wn][wm * 64 + m * 16 + khi * 4 + r] = v;
        }
    }
    // col sums over this wave's 64 rows
    #pragma unroll
    for (int n = 0; n < 4; ++n) {
        float v = 0.f;
        #pragma unroll
        for (int m = 0; m < 4; ++m)
            v += acc[m][n][0] + acc[m][n][1] + acc[m][n][2] + acc[m][n][3];
        v += __shfl_xor(v, 16);
        v += __shfl_xor(v, 32);
        if (khi == 0) cbuf[wm][wn * 64 + n * 16 + llo] = v;
    }
    __syncthreads();
    if (tid < 128) {
        rp[(size_t)bj * 8192 + bi * 128 + tid] = rbuf[0][tid] + rbuf[1][tid];
        cp[(size_t)bi * 8192 + bj * 128 + tid] = cbuf[0][tid] + cbuf[1][tid];
    }
}

// ---- per-row logs, block partial sums ----
__global__ __launch_bounds__(256) void clip_fin1_k(const float* __restrict__ rp,
                                                   const float* __restrict__ cp,
                                                   const float* __restrict__ dg,
                                                   float* __restrict__ part) {
    int i = blockIdx.x * 256 + threadIdx.x;
    float rs = 0.f, cs = 0.f;
    #pragma unroll 8
    for (int b = 0; b < 64; ++b) rs += rp[(size_t)b * 8192 + i];
    #pragma unroll 8
    for (int b = 0; b < 64; ++b) cs += cp[(size_t)b * 8192 + i];
    float c = 0.5f * (logf(rs) + logf(cs)) - dg[i];
    #pragma unroll
    for (int o = 1; o < 64; o <<= 1) c += __shfl_xor(c, o);
    __shared__ float sb[4];
    if ((threadIdx.x & 63) == 0) sb[threadIdx.x >> 6] = c;
    __syncthreads();
    if (threadIdx.x == 0) part[blockIdx.x] = sb[0] + sb[1] + sb[2] + sb[3];
}

__global__ void clip_fin2_k(const float* __restrict__ part, float* __restrict__ out) {
    float v = (threadIdx.x < 32) ? part[threadIdx.x] : 0.f;
    #pragma unroll
    for (int o = 1; o < 64; o <<= 1) v += __shfl_xor(v, o);
    if (threadIdx.x == 0) out[0] = v * (1.f / 8192.f);
}

extern "C" void kernel_launch(void* const* d_in, const int* in_sizes, int n_in,
                              void* d_out, int out_size, void* d_ws, size_t ws_size,
                              hipStream_t stream) {
    const float* zi = (const float*)d_in[0];
    const float* zj = (const float*)d_in[1];
    float* out = (float*)d_out;
    char* ws = (char*)d_ws;

    unsigned int* zi8 = (unsigned int*)(ws);
    unsigned int* zj8 = (unsigned int*)(ws + (size_t)8 * 1024 * 1024);
    float* rp   = (float*)(ws + (size_t)16 * 1024 * 1024);   // 2 MB (64 panels)
    float* cp   = (float*)(ws + (size_t)18 * 1024 * 1024);   // 2 MB (64 panels)
    float* dg   = (float*)(ws + (size_t)20 * 1024 * 1024);
    float* part = (float*)(ws + (size_t)20 * 1024 * 1024 + 32768);

    clip_norm_k<<<8192, 256, 0, stream>>>(zi, zi8, 2.0f);   // temp x2 folded into zi
    clip_norm_k<<<8192, 256, 0, stream>>>(zj, zj8, 1.0f);
    clip_gemm_k<<<4096, 256, 0, stream>>>((const unsigned char*)zi8,
                                          (const unsigned char*)zj8, rp, cp, dg);
    clip_fin1_k<<<32, 256, 0, stream>>>(rp, cp, dg, part);
    clip_fin2_k<<<1, 64, 0, stream>>>(part, out);
}

// Round 18
// 131.283 us; speedup vs baseline: 2.0648x; 2.0648x over previous
//
#include <hip/hip_runtime.h>
#include <hip/hip_bf16.h>

// CLIP loss: B=8192, D=1024, temp=0.5.
// loss = mean_i [ 0.5*(log sum_j exp(s_ij) + log sum_j exp(s_ji)) - s_ii ],
// s = (zi_n @ zj_n^T) * 2.  |s| <= 2 -> exp safe, no max trick.
//
// R18 = R15 (best: GEMM 120us, clean alloc) + micro-polish:
//  (a) loop body reordered to m201 phase order: ds_reads(t) first, then
//      STAGE(t+1) issue (overlaps MFMA startup), then MFMA cluster.
//  (b) T5 setprio(1/0) around MFMA cluster.
//  (c) both norm passes fused into one launch (16384 blocks).
// Core unchanged: 16x16x128 scaled fp8 (unit scales), 128x128 tile, 4 waves
// (2x2), A+B LDS dbuf, T3 2-phase (1 barrier/tile, vmcnt(0)+lgkm(0)),
// L2 supertile swizzle, chunk swizzle cphys = clog ^ (row&7) both sides.
// Allocator rule (R6-R17): ONLY this 256-thr/(256,2) operand set
// (af[4],bfr[4],acc[4][4] f32x4->AGPR) avoids the scaled-MFMA spill.
//
// ws: [0,8M) zi8 (x2 temp folded), [8M,16M) zj8, [16M,18M) rp[64][8192],
//     [18M,20M) cp[64][8192], [20M,+32K) dg[8192], then part[32].

using f32x4 = __attribute__((ext_vector_type(4))) float;
using i32x8 = __attribute__((ext_vector_type(8))) int;
using i32x4 = __attribute__((ext_vector_type(4))) int;

#define USCL 0x7F7F7F7Fu   // E8M0 = 127 -> scale 1.0 in every byte

__device__ __forceinline__ void async16(const unsigned char* g, unsigned char* l) {
    __builtin_amdgcn_global_load_lds(
        (const __attribute__((address_space(1))) void*)g,
        (__attribute__((address_space(3))) void*)l, 16, 0, 0);
}

// ---- kernel 1: row-normalize fp32 -> fp8 e4m3, both inputs in one launch ----
__global__ __launch_bounds__(256) void clip_norm2_k(const float* __restrict__ zi,
                                                    const float* __restrict__ zj,
                                                    unsigned int* __restrict__ oi,
                                                    unsigned int* __restrict__ oj) {
    const int isJ = blockIdx.x >> 13;        // 0: zi, 1: zj
    const int row = blockIdx.x & 8191;
    const float* in = isJ ? zj : zi;
    unsigned int* out = isJ ? oj : oi;
    const float extra = isJ ? 1.0f : 2.0f;   // temp x2 folded into zi side
    const float4* ip = reinterpret_cast<const float4*>(in + (size_t)row * 1024);
    float4 v = ip[threadIdx.x];
    float ss = v.x * v.x + v.y * v.y + v.z * v.z + v.w * v.w;
    #pragma unroll
    for (int o = 1; o < 64; o <<= 1) ss += __shfl_xor(ss, o);
    __shared__ float sb[4];
    if ((threadIdx.x & 63) == 0) sb[threadIdx.x >> 6] = ss;
    __syncthreads();
    float tot = sb[0] + sb[1] + sb[2] + sb[3];
    float scl = extra / fmaxf(sqrtf(tot), 1e-12f);
    int p = __builtin_amdgcn_cvt_pk_fp8_f32(v.x * scl, v.y * scl, 0, false);
    p = __builtin_amdgcn_cvt_pk_fp8_f32(v.z * scl, v.w * scl, p, true);
    out[(size_t)row * 256 + threadIdx.x] = (unsigned int)p;
}

// A/B fragment from swizzled LDS (R9-verified): row in tile, khi = l>>4.
__device__ __forceinline__ i32x8 ldfrag(const unsigned char* buf, int row, int khi) {
    int p0 = (2 * khi) ^ (row & 7);
    int p1 = (2 * khi + 1) ^ (row & 7);
    i32x4 lo = *reinterpret_cast<const i32x4*>(buf + row * 128 + p0 * 16);
    i32x4 hi = *reinterpret_cast<const i32x4*>(buf + row * 128 + p1 * 16);
    i32x8 r;
    r[0] = lo[0]; r[1] = lo[1]; r[2] = lo[2]; r[3] = lo[3];
    r[4] = hi[0]; r[5] = hi[1]; r[6] = hi[2]; r[7] = hi[3];
    return r;
}

__global__ __launch_bounds__(256, 2) void clip_gemm_k(
    const unsigned char* __restrict__ A,   // zi8 [8192][1024]
    const unsigned char* __restrict__ Bm,  // zj8 [8192][1024]
    float* __restrict__ rp, float* __restrict__ cp, float* __restrict__ dg) {
    __shared__ unsigned char bA0[16384], bB0[16384], bA1[16384], bB1[16384];
    __shared__ float rbuf[2][128];
    __shared__ float cbuf[2][128];

    // L2-supertile swizzle (R10-verified: FETCH 266->37 MB).
    const int c_x = blockIdx.x & 7;
    const int q = blockIdx.x >> 3;           // 0..511
    const int s = q >> 6;                    // supertile 0..7 (temporal)
    const int p = q & 63;                    // position in 8x8 supertile
    const int bi = c_x * 8 + (p >> 3);       // 0..63
    const int bj = s * 8 + (p & 7);          // 0..63
    const int tid = threadIdx.x;
    const int l = tid & 63, w = tid >> 6;
    const int wm = w >> 1, wn = w & 1;       // 2x2 wave grid, per-wave 64x64
    const int llo = l & 15, khi = l >> 4;

    f32x4 acc[4][4] = {};

    const unsigned char* Ag = A + (size_t)(bi * 128) * 1024;
    const unsigned char* Bg = Bm + (size_t)(bj * 128) * 1024;

    // per-thread staging offsets (4 sweeps x 256 thr x 16B = one [128][128B] buf)
    int soff[4];
    #pragma unroll
    for (int u = 0; u < 4; ++u) {
        int idx = u * 256 + tid;
        int srow = idx >> 3;
        int clog = idx & 7;
        soff[u] = srow * 1024 + ((clog ^ (srow & 7)) * 16);
    }
    const int ldst = tid * 16;   // linear dest within each sweep block

#define STAGE(ktB, bufA, bufB)                                            \
    _Pragma("unroll") for (int u = 0; u < 4; ++u)                         \
        async16(Ag + (ktB) + soff[u], (bufA) + u * 4096 + ldst);          \
    _Pragma("unroll") for (int u = 0; u < 4; ++u)                         \
        async16(Bg + (ktB) + soff[u], (bufB) + u * 4096 + ldst);

    // prologue: stage tile 0, drain, sync
    STAGE(0, bA0, bB0)
    asm volatile("s_waitcnt vmcnt(0)" ::: "memory");
    __builtin_amdgcn_s_barrier();
    __builtin_amdgcn_sched_barrier(0);

    // 2-phase, m201 phase order inside the tile: ds_reads(t) -> STAGE(t+1)
    // issue -> setprio+MFMA -> vmcnt(0)+lgkm(0) -> ONE barrier.
    for (int t = 0; t < 8; ++t) {
        const unsigned char* Ac = (t & 1) ? bA1 : bA0;
        const unsigned char* Bc = (t & 1) ? bB1 : bB0;
        unsigned char* Asg = (t & 1) ? bA0 : bA1;
        unsigned char* Bsg = (t & 1) ? bB0 : bB1;

        i32x8 af[4], bfr[4];
        #pragma unroll
        for (int m = 0; m < 4; ++m)
            af[m] = ldfrag(Ac, wm * 64 + m * 16 + llo, khi);
        #pragma unroll
        for (int n = 0; n < 4; ++n)
            bfr[n] = ldfrag(Bc, wn * 64 + n * 16 + llo, khi);

        if (t <= 6) { STAGE((t + 1) * 128, Asg, Bsg) }

        __builtin_amdgcn_s_setprio(1);
        #pragma unroll
        for (int m = 0; m < 4; ++m)
            #pragma unroll
            for (int n = 0; n < 4; ++n)
                acc[m][n] = __builtin_amdgcn_mfma_scale_f32_16x16x128_f8f6f4(
                    af[m], bfr[n], acc[m][n], 0, 0, 0, USCL, 0, USCL);
        __builtin_amdgcn_s_setprio(0);

        if (t <= 6) {
            asm volatile("s_waitcnt vmcnt(0) lgkmcnt(0)" ::: "memory");
            __builtin_amdgcn_s_barrier();
            __builtin_amdgcn_sched_barrier(0);
        }
    }
#undef STAGE

    // ---- epilogue (R9/R10-verified 16x16 C/D mapping: col=llo, row=khi*4+reg) ----
    if (bi == bj && wm == wn) {
        #pragma unroll
        for (int m = 0; m < 4; ++m)
            #pragma unroll
            for (int r = 0; r < 4; ++r)
                if (khi * 4 + r == llo)
                    dg[bi * 128 + wm * 64 + m * 16 + llo] = acc[m][m][r];
    }

    #pragma unroll
    for (int m = 0; m < 4; ++m)
        #pragma unroll
        for (int n = 0; n < 4; ++n)
            #pragma unroll
            for (int r = 0; r < 4; ++r)
                acc[m][n][r] = exp2f(acc[m][n][r] * 1.44269504f);

    // row sums over this wave's 64 cols
    #pragma unroll
    for (int m = 0; m < 4; ++m) {
        #pragma unroll
        for (int r = 0; r < 4; ++r) {
            float v = acc[m][0][r] + acc[m][1][r] + acc[m][2][r] + acc[m][3][r];
            v += __shfl_xor(v, 1);
            v += __shfl_xor(v, 2);
            v += __shfl_xor(v, 4);
            v += __shfl_xor(v, 8);
            if (llo == 0) rbuf[wn][wm * 64 + m * 16 + khi * 4 + r] = v;
        }
    }
    // col sums over this wave's 64 rows
    #pragma unroll
    for (int n = 0; n < 4; ++n) {
        float v = 0.f;
        #pragma unroll
        for (int m = 0; m < 4; ++m)
            v += acc[m][n][0] + acc[m][n][1] + acc[m][n][2] + acc[m][n][3];
        v += __shfl_xor(v, 16);
        v += __shfl_xor(v, 32);
        if (khi == 0) cbuf[wm][wn * 64 + n * 16 + llo] = v;
    }
    __syncthreads();
    if (tid < 128) {
        rp[(size_t)bj * 8192 + bi * 128 + tid] = rbuf[0][tid] + rbuf[1][tid];
        cp[(size_t)bi * 8192 + bj * 128 + tid] = cbuf[0][tid] + cbuf[1][tid];
    }
}

// ---- per-row logs, block partial sums ----
__global__ __launch_bounds__(256) void clip_fin1_k(const float* __restrict__ rp,
                                                   const float* __restrict__ cp,
                                                   const float* __restrict__ dg,
                                                   float* __restrict__ part) {
    int i = blockIdx.x * 256 + threadIdx.x;
    float rs = 0.f, cs = 0.f;
    #pragma unroll 8
    for (int b = 0; b < 64; ++b) rs += rp[(size_t)b * 8192 + i];
    #pragma unroll 8
    for (int b = 0; b < 64; ++b) cs += cp[(size_t)b * 8192 + i];
    float c = 0.5f * (logf(rs) + logf(cs)) - dg[i];
    #pragma unroll
    for (int o = 1; o < 64; o <<= 1) c += __shfl_xor(c, o);
    __shared__ float sb[4];
    if ((threadIdx.x & 63) == 0) sb[threadIdx.x >> 6] = c;
    __syncthreads();
    if (threadIdx.x == 0) part[blockIdx.x] = sb[0] + sb[1] + sb[2] + sb[3];
}

__global__ void clip_fin2_k(const float* __restrict__ part, float* __restrict__ out) {
    float v = (threadIdx.x < 32) ? part[threadIdx.x] : 0.f;
    #pragma unroll
    for (int o = 1; o < 64; o <<= 1) v += __shfl_xor(v, o);
    if (threadIdx.x == 0) out[0] = v * (1.f / 8192.f);
}

extern "C" void kernel_launch(void* const* d_in, const int* in_sizes, int n_in,
                              void* d_out, int out_size, void* d_ws, size_t ws_size,
                              hipStream_t stream) {
    const float* zi = (const float*)d_in[0];
    const float* zj = (const float*)d_in[1];
    float* out = (float*)d_out;
    char* ws = (char*)d_ws;

    unsigned int* zi8 = (unsigned int*)(ws);
    unsigned int* zj8 = (unsigned int*)(ws + (size_t)8 * 1024 * 1024);
    float* rp   = (float*)(ws + (size_t)16 * 1024 * 1024);   // 2 MB (64 panels)
    float* cp   = (float*)(ws + (size_t)18 * 1024 * 1024);   // 2 MB (64 panels)
    float* dg   = (float*)(ws + (size_t)20 * 1024 * 1024);
    float* part = (float*)(ws + (size_t)20 * 1024 * 1024 + 32768);

    clip_norm2_k<<<16384, 256, 0, stream>>>(zi, zj, zi8, zj8);
    clip_gemm_k<<<4096, 256, 0, stream>>>((const unsigned char*)zi8,
                                          (const unsigned char*)zj8, rp, cp, dg);
    clip_fin1_k<<<32, 256, 0, stream>>>(rp, cp, dg, part);
    clip_fin2_k<<<1, 64, 0, stream>>>(part, out);
}

// Round 19
// 125.623 us; speedup vs baseline: 2.1579x; 1.0451x over previous
//
#include <hip/hip_runtime.h>
#include <hip/hip_bf16.h>

// CLIP loss: B=8192, D=1024, temp=0.5.  FINAL (= R15, session best: 125.7us).
// loss = mean_i [ 0.5*(log sum_j exp(s_ij) + log sum_j exp(s_ji)) - s_ii ],
// s = (zi_n @ zj_n^T) * 2.  |s| <= 2 -> exp safe, no max trick.
//
// Structure: norm fp32->fp8 e4m3 (temp folded into zi side);
// GEMM: mfma_scale_f32_16x16x128_f8f6f4 (unit scales), 128x128 tile,
// 256 thr / 4 waves (2x2), per-wave 64x64 acc[4][4] f32x4 (->AGPR, the ONLY
// spill-free operand set for this intrinsic: R6-R14 evidence), A+B LDS
// double-buffer (67.5KB, 2 blocks/CU), T3 2-phase schedule (STAGE(t+1) at
// top, one vmcnt(0)+lgkm(0)+barrier per tile), L2 supertile swizzle
// (FETCH 266->37MB), 16B-chunk swizzle cphys = clog ^ (row&7) both sides.
// Fused exp row/col partial sums in the epilogue; never materializes sim.
//
// ws: [0,8M) zi8 (x2 temp folded), [8M,16M) zj8, [16M,18M) rp[64][8192],
//     [18M,20M) cp[64][8192], [20M,+32K) dg[8192], then part[32].

using f32x4 = __attribute__((ext_vector_type(4))) float;
using i32x8 = __attribute__((ext_vector_type(8))) int;
using i32x4 = __attribute__((ext_vector_type(4))) int;

#define USCL 0x7F7F7F7Fu   // E8M0 = 127 -> scale 1.0 in every byte

__device__ __forceinline__ void async16(const unsigned char* g, unsigned char* l) {
    __builtin_amdgcn_global_load_lds(
        (const __attribute__((address_space(1))) void*)g,
        (__attribute__((address_space(3))) void*)l, 16, 0, 0);
}

// ---- kernel 1: row-normalize fp32 -> fp8 e4m3, extra scale folded ----
__global__ __launch_bounds__(256) void clip_norm_k(const float* __restrict__ in,
                                                   unsigned int* __restrict__ out,
                                                   float extra) {
    int row = blockIdx.x;
    const float4* ip = reinterpret_cast<const float4*>(in + (size_t)row * 1024);
    float4 v = ip[threadIdx.x];
    float ss = v.x * v.x + v.y * v.y + v.z * v.z + v.w * v.w;
    #pragma unroll
    for (int o = 1; o < 64; o <<= 1) ss += __shfl_xor(ss, o);
    __shared__ float sb[4];
    if ((threadIdx.x & 63) == 0) sb[threadIdx.x >> 6] = ss;
    __syncthreads();
    float tot = sb[0] + sb[1] + sb[2] + sb[3];
    float scl = extra / fmaxf(sqrtf(tot), 1e-12f);
    int p = __builtin_amdgcn_cvt_pk_fp8_f32(v.x * scl, v.y * scl, 0, false);
    p = __builtin_amdgcn_cvt_pk_fp8_f32(v.z * scl, v.w * scl, p, true);
    out[(size_t)row * 256 + threadIdx.x] = (unsigned int)p;
}

// Read a 32B fp8 A/B fragment for 16x16x128: row in tile, khi = l>>4 (0..3)
// covers k = khi*32 .. khi*32+31. LDS row = 8 chunks of 16B, phys = log^(row&7).
__device__ __forceinline__ i32x8 ldfrag(const unsigned char* buf, int row, int khi) {
    int p0 = (2 * khi) ^ (row & 7);
    int p1 = (2 * khi + 1) ^ (row & 7);
    i32x4 lo = *reinterpret_cast<const i32x4*>(buf + row * 128 + p0 * 16);
    i32x4 hi = *reinterpret_cast<const i32x4*>(buf + row * 128 + p1 * 16);
    i32x8 r;
    r[0] = lo[0]; r[1] = lo[1]; r[2] = lo[2]; r[3] = lo[3];
    r[4] = hi[0]; r[5] = hi[1]; r[6] = hi[2]; r[7] = hi[3];
    return r;
}

__global__ __launch_bounds__(256, 2) void clip_gemm_k(
    const unsigned char* __restrict__ A,   // zi8 [8192][1024]
    const unsigned char* __restrict__ Bm,  // zj8 [8192][1024]
    float* __restrict__ rp, float* __restrict__ cp, float* __restrict__ dg) {
    __shared__ unsigned char bA0[16384], bB0[16384], bA1[16384], bB1[16384];
    __shared__ float rbuf[2][128];
    __shared__ float cbuf[2][128];

    // L2-supertile swizzle (R10-verified: FETCH 266->37 MB).
    const int c_x = blockIdx.x & 7;
    const int q = blockIdx.x >> 3;           // 0..511
    const int s = q >> 6;                    // supertile 0..7 (temporal)
    const int p = q & 63;                    // position in 8x8 supertile
    const int bi = c_x * 8 + (p >> 3);       // 0..63
    const int bj = s * 8 + (p & 7);          // 0..63
    const int tid = threadIdx.x;
    const int l = tid & 63, w = tid >> 6;
    const int wm = w >> 1, wn = w & 1;       // 2x2 wave grid, per-wave 64x64
    const int llo = l & 15, khi = l >> 4;

    f32x4 acc[4][4] = {};

    const unsigned char* Ag = A + (size_t)(bi * 128) * 1024;
    const unsigned char* Bg = Bm + (size_t)(bj * 128) * 1024;

    // per-thread staging offsets (4 sweeps x 256 thr x 16B = one [128][128B] buf)
    int soff[4];
    #pragma unroll
    for (int u = 0; u < 4; ++u) {
        int idx = u * 256 + tid;
        int srow = idx >> 3;
        int clog = idx & 7;
        soff[u] = srow * 1024 + ((clog ^ (srow & 7)) * 16);
    }
    const int ldst = tid * 16;   // linear dest within each sweep block

#define STAGE(ktB, bufA, bufB)                                            \
    _Pragma("unroll") for (int u = 0; u < 4; ++u)                         \
        async16(Ag + (ktB) + soff[u], (bufA) + u * 4096 + ldst);          \
    _Pragma("unroll") for (int u = 0; u < 4; ++u)                         \
        async16(Bg + (ktB) + soff[u], (bufB) + u * 4096 + ldst);

    // prologue: stage tile 0, drain, sync
    STAGE(0, bA0, bB0)
    asm volatile("s_waitcnt vmcnt(0)" ::: "memory");
    __builtin_amdgcn_s_barrier();
    __builtin_amdgcn_sched_barrier(0);

    // T3 minimum 2-phase: stage(next) at top; compute current; lgkm(0)+
    // vmcnt(0); ONE barrier. Stage target buf[(t+1)&1] was read at t-1 and
    // drained before t-1's barrier -> safe to overwrite.
    for (int t = 0; t < 8; ++t) {
        const unsigned char* Ac = (t & 1) ? bA1 : bA0;
        const unsigned char* Bc = (t & 1) ? bB1 : bB0;
        unsigned char* Asg = (t & 1) ? bA0 : bA1;
        unsigned char* Bsg = (t & 1) ? bB0 : bB1;

        if (t <= 6) { STAGE((t + 1) * 128, Asg, Bsg) }

        i32x8 af[4], bfr[4];
        #pragma unroll
        for (int m = 0; m < 4; ++m)
            af[m] = ldfrag(Ac, wm * 64 + m * 16 + llo, khi);
        #pragma unroll
        for (int n = 0; n < 4; ++n)
            bfr[n] = ldfrag(Bc, wn * 64 + n * 16 + llo, khi);
        #pragma unroll
        for (int m = 0; m < 4; ++m)
            #pragma unroll
            for (int n = 0; n < 4; ++n)
                acc[m][n] = __builtin_amdgcn_mfma_scale_f32_16x16x128_f8f6f4(
                    af[m], bfr[n], acc[m][n], 0, 0, 0, USCL, 0, USCL);

        if (t <= 6) {
            asm volatile("s_waitcnt vmcnt(0) lgkmcnt(0)" ::: "memory");
            __builtin_amdgcn_s_barrier();
            __builtin_amdgcn_sched_barrier(0);
        }
    }
#undef STAGE

    // ---- epilogue (R9/R10-verified 16x16 C/D mapping: col=llo, row=khi*4+reg) ----
    if (bi == bj && wm == wn) {
        #pragma unroll
        for (int m = 0; m < 4; ++m)
            #pragma unroll
            for (int r = 0; r < 4; ++r)
                if (khi * 4 + r == llo)
                    dg[bi * 128 + wm * 64 + m * 16 + llo] = acc[m][m][r];
    }

    #pragma unroll
    for (int m = 0; m < 4; ++m)
        #pragma unroll
        for (int n = 0; n < 4; ++n)
            #pragma unroll
            for (int r = 0; r < 4; ++r)
                acc[m][n][r] = exp2f(acc[m][n][r] * 1.44269504f);

    // row sums over this wave's 64 cols
    #pragma unroll
    for (int m = 0; m < 4; ++m) {
        #pragma unroll
        for (int r = 0; r < 4; ++r) {
            float v = acc[m][0][r] + acc[m][1][r] + acc[m][2][r] + acc[m][3][r];
            v += __shfl_xor(v, 1);
            v += __shfl_xor(v, 2);
            v += __shfl_xor(v, 4);
            v += __shfl_xor(v, 8);
            if (llo == 0) rbuf[wn][wm * 64 + m * 16 + khi * 4 + r] = v;
        }
    }
    // col sums over this wave's 64 rows
    #pragma unroll
    for (int n = 0; n < 4; ++n) {
        float v = 0.f;
        #pragma unroll
        for (int m = 0; m < 4; ++m)
            v += acc[m][n][0] + acc[m][n][1] + acc[m][n][2] + acc[m][n][3];
        v += __shfl_xor(v, 16);
        v += __shfl_xor(v, 32);
        if (khi == 0) cbuf[wm][wn * 64 + n * 16 + llo] = v;
    }
    __syncthreads();
    if (tid < 128) {
        rp[(size_t)bj * 8192 + bi * 128 + tid] = rbuf[0][tid] + rbuf[1][tid];
        cp[(size_t)bi * 8192 + bj * 128 + tid] = cbuf[0][tid] + cbuf[1][tid];
    }
}

// ---- per-row logs, block partial sums ----
__global__ __launch_bounds__(256) void clip_fin1_k(const float* __restrict__ rp,
                                                   const float* __restrict__ cp,
                                                   const float* __restrict__ dg,
                                                   float* __restrict__ part) {
    int i = blockIdx.x * 256 + threadIdx.x;
    float rs = 0.f, cs = 0.f;
    #pragma unroll 8
    for (int b = 0; b < 64; ++b) rs += rp[(size_t)b * 8192 + i];
    #pragma unroll 8
    for (int b = 0; b < 64; ++b) cs += cp[(size_t)b * 8192 + i];
    float c = 0.5f * (logf(rs) + logf(cs)) - dg[i];
    #pragma unroll
    for (int o = 1; o < 64; o <<= 1) c += __shfl_xor(c, o);
    __shared__ float sb[4];
    if ((threadIdx.x & 63) == 0) sb[threadIdx.x >> 6] = c;
    __syncthreads();
    if (threadIdx.x == 0) part[blockIdx.x] = sb[0] + sb[1] + sb[2] + sb[3];
}

__global__ void clip_fin2_k(const float* __restrict__ part, float* __restrict__ out) {
    float v = (threadIdx.x < 32) ? part[threadIdx.x] : 0.f;
    #pragma unroll
    for (int o = 1; o < 64; o <<= 1) v += __shfl_xor(v, o);
    if (threadIdx.x == 0) out[0] = v * (1.f / 8192.f);
}

extern "C" void kernel_launch(void* const* d_in, const int* in_sizes, int n_in,
                              void* d_out, int out_size, void* d_ws, size_t ws_size,
                              hipStream_t stream) {
    const float* zi = (const float*)d_in[0];
    const float* zj = (const float*)d_in[1];
    float* out = (float*)d_out;
    char* ws = (char*)d_ws;

    unsigned int* zi8 = (unsigned int*)(ws);
    unsigned int* zj8 = (unsigned int*)(ws + (size_t)8 * 1024 * 1024);
    float* rp   = (float*)(ws + (size_t)16 * 1024 * 1024);   // 2 MB (64 panels)
    float* cp   = (float*)(ws + (size_t)18 * 1024 * 1024);   // 2 MB (64 panels)
    float* dg   = (float*)(ws + (size_t)20 * 1024 * 1024);
    float* part = (float*)(ws + (size_t)20 * 1024 * 1024 + 32768);

    clip_norm_k<<<8192, 256, 0, stream>>>(zi, zi8, 2.0f);   // temp x2 folded into zi
    clip_norm_k<<<8192, 256, 0, stream>>>(zj, zj8, 1.0f);
    clip_gemm_k<<<4096, 256, 0, stream>>>((const unsigned char*)zi8,
                                          (const unsigned char*)zj8, rp, cp, dg);
    clip_fin1_k<<<32, 256, 0, stream>>>(rp, cp, dg, part);
    clip_fin2_k<<<1, 64, 0, stream>>>(part, out);
}